// Round 8
// baseline (669.960 us; speedup 1.0000x reference)
//
#include <hip/hip_runtime.h>
#include <hip/hip_bf16.h>
#include <math.h>

#define NUM_EMB 8192
#define DIM 512
#define NROWS 16384   // 32*512
#define NPART 4096    // gather_loss partial sums (one per block)

typedef unsigned short ushort;
typedef unsigned long long ull;
typedef __attribute__((ext_vector_type(8))) short short8;
typedef __attribute__((ext_vector_type(4))) float floatx4;

// ---------------- helpers ----------------
__device__ __forceinline__ ushort f2bf(float f) {
    unsigned u = __float_as_uint(f);
    unsigned r = (u + 0x7fffu + ((u >> 16) & 1u)) >> 16;   // RNE
    return (ushort)r;
}
__device__ __forceinline__ float bf2f(ushort h) {
    return __uint_as_float(((unsigned)h) << 16);
}
__device__ __forceinline__ unsigned fmap(float f) {       // monotone float->uint
    unsigned u = __float_as_uint(f);
    return (u & 0x80000000u) ? ~u : (u | 0x80000000u);
}
__device__ __forceinline__ float funmap(unsigned m) {
    return __uint_as_float((m & 0x80000000u) ? (m ^ 0x80000000u) : ~m);
}
__device__ __forceinline__ void gld16(const void* g, void* l) {
    __builtin_amdgcn_global_load_lds(
        (const __attribute__((address_space(1))) void*)g,
        (__attribute__((address_space(3))) void*)l, 16, 0, 0);
}

// ---------- fused split for BOTH x and cb: bf16 hi/lo + row sumsq + packed init ----------
// one wave per row; blocks cover x rows then cb rows
__global__ __launch_bounds__(256) void split_all_k(const float* __restrict__ x,
    const float* __restrict__ cb,
    ushort* __restrict__ xh, ushort* __restrict__ xl,
    ushort* __restrict__ ch, ushort* __restrict__ cl,
    float* __restrict__ x2, float* __restrict__ e2, ull* __restrict__ packed)
{
    int gid  = blockIdx.x * blockDim.x + threadIdx.x;
    int row  = gid >> 6;
    int lane = threadIdx.x & 63;
    if (row >= NROWS + NUM_EMB) return;
    const float* src; ushort* hi; ushort* lo; float* ss; int r;
    if (row < NROWS) { r = row;         src = x;  hi = xh; lo = xl; ss = x2; }
    else             { r = row - NROWS; src = cb; hi = ch; lo = cl; ss = e2; }
    const float4* rp = (const float4*)(src + (size_t)r * DIM);
    ushort4* h4 = (ushort4*)(hi + (size_t)r * DIM);
    ushort4* l4 = (ushort4*)(lo + (size_t)r * DIM);
    float s = 0.f;
#pragma unroll
    for (int i = lane; i < DIM / 4; i += 64) {
        float4 v = rp[i];
        s += v.x * v.x + v.y * v.y + v.z * v.z + v.w * v.w;
        ushort4 h, l;
        h.x = f2bf(v.x); l.x = f2bf(v.x - bf2f(h.x));
        h.y = f2bf(v.y); l.y = f2bf(v.y - bf2f(h.y));
        h.z = f2bf(v.z); l.z = f2bf(v.z - bf2f(h.z));
        h.w = f2bf(v.w); l.w = f2bf(v.w - bf2f(h.w));
        h4[i] = h; l4[i] = l;
    }
#pragma unroll
    for (int off = 32; off > 0; off >>= 1) s += __shfl_down(s, off, 64);
    if (lane == 0) {
        ss[r] = s;
        if (row < NROWS) packed[row] = ~0ull;
    }
}

// ---------- MFMA distance + argmin (16x16x32 bf16, 3-pass hi/lo split) ----------
// grid (128, 64): 128x128 tile of rows x codes.
// B (codebook tile, shared by all 4 waves) staged via LDS with the R4
// 0-conflict XOR swizzle. A fragments are wave-private -> loaded DIRECT
// global->VGPR (coalesced 16 rows x 64B, L1/L2/L3-resident), software-
// pipelined one m-group ahead. This halves LDS-pipe traffic (96->48 KB per
// block-kk), which R7's model showed was co-bottleneck with MFMA.
__global__ __launch_bounds__(256, 4) void dist_mfma_k(
    const ushort* __restrict__ xh, const ushort* __restrict__ xl,
    const ushort* __restrict__ ch, const ushort* __restrict__ cl,
    const float* __restrict__ e2, ull* __restrict__ packed)
{
    __shared__ ushort Bh[128 * 32];   // 8 KB
    __shared__ ushort Bl[128 * 32];   // 8 KB

    const int tid  = threadIdx.x;
    const int lane = tid & 63;
    const int w    = tid >> 6;
    const int wm   = w >> 1, wn = w & 1;
    const int row0 = blockIdx.x * 128;
    const int col0 = blockIdx.y * 128;

    floatx4 acc[4][4];
#pragma unroll
    for (int m = 0; m < 4; ++m)
#pragma unroll
        for (int n = 0; n < 4; ++n) acc[m][n] = (floatx4){0.f, 0.f, 0.f, 0.f};

    // B staging chunk map: chunk c (0..511) -> row c>>2, LDS cell c&3 at lds
    // elem-off c*8; global segment fetched = (c&3) ^ ((c>>3)&3)  [swizzle]
    const int c0 = tid, c1 = tid + 256;
    const int gb0 = (col0 + (c0 >> 2)) * DIM + (((c0 & 3) ^ ((c0 >> 3) & 3)) * 8);
    const int gb1 = (col0 + (c1 >> 2)) * DIM + (((c1 & 3) ^ ((c1 >> 3) & 3)) * 8);
    const int l0 = c0 * 8, l1 = c1 * 8;

    // B fragment base: row (lane&15), cell (lane>>4) ^ ((lane>>1)&3)
    const int fr = (lane & 15) * 32 + (((lane >> 4) ^ ((lane >> 1) & 3)) * 8);

    // A fragment global base: row = row0 + wm*64 + (lane&15), k-off (lane>>4)*8
    const size_t abase = (size_t)(row0 + wm * 64 + (lane & 15)) * DIM + (lane >> 4) * 8;

    // prologue: A frag (m=0, kk=0)
    short8 ahc = *(const short8*)(xh + abase);
    short8 alc = *(const short8*)(xl + abase);

    for (int kk = 0; kk < 16; ++kk) {
        const int dk = kk * 32;
        __syncthreads();   // previous iteration's B reads complete
        gld16(&ch[gb0 + dk], &Bh[l0]);  gld16(&ch[gb1 + dk], &Bh[l1]);
        gld16(&cl[gb0 + dk], &Bl[l0]);  gld16(&cl[gb1 + dk], &Bl[l1]);
        __syncthreads();   // B staged (vmcnt0 also lands in-flight A prefetch)

        short8 bh[4], bl[4];
#pragma unroll
        for (int n = 0; n < 4; ++n) {
            const int o = (wn * 64 + n * 16) * 32 + fr;
            bh[n] = *(const short8*)&Bh[o];
            bl[n] = *(const short8*)&Bl[o];
        }

#pragma unroll
        for (int m = 0; m < 4; ++m) {
            // prefetch next A frag: (m+1, kk) or (0, kk+1); the kk=15,m=3 case
            // reads 16B past the row into xl's region (unused value, safe).
            const size_t anext = (m < 3) ? (abase + (size_t)((m + 1) * 16) * DIM + dk)
                                         : (abase + (size_t)(kk + 1) * 32);
            short8 ahn = *(const short8*)(xh + anext);
            short8 aln = *(const short8*)(xl + anext);
#pragma unroll
            for (int n = 0; n < 4; ++n) {
                acc[m][n] = __builtin_amdgcn_mfma_f32_16x16x32_bf16(ahc, bh[n], acc[m][n], 0, 0, 0);
                acc[m][n] = __builtin_amdgcn_mfma_f32_16x16x32_bf16(ahc, bl[n], acc[m][n], 0, 0, 0);
                acc[m][n] = __builtin_amdgcn_mfma_f32_16x16x32_bf16(alc, bh[n], acc[m][n], 0, 0, 0);
            }
            ahc = ahn; alc = aln;
        }
    }

    // epilogue: v = e2[c] - 2*dot ; argmin with first-occurrence tie-break
    float e2v[4];
    int   cidx[4];
#pragma unroll
    for (int n = 0; n < 4; ++n) {
        cidx[n] = col0 + wn * 64 + n * 16 + (lane & 15);
        e2v[n]  = e2[cidx[n]];
    }
#pragma unroll
    for (int m = 0; m < 4; ++m) {
#pragma unroll
        for (int r = 0; r < 4; ++r) {
            float bv = INFINITY; int bi = 0x7fffffff;
#pragma unroll
            for (int n = 0; n < 4; ++n) {        // ascending code order
                float v = e2v[n] - 2.f * acc[m][n][r];
                if (v < bv) { bv = v; bi = cidx[n]; }
            }
#pragma unroll
            for (int mk = 1; mk < 16; mk <<= 1) {  // 16-lane butterfly (same quad group)
                float ov = __shfl_xor(bv, mk, 64);
                int   oi = __shfl_xor(bi, mk, 64);
                if (ov < bv || (ov == bv && oi < bi)) { bv = ov; bi = oi; }
            }
            if ((lane & 15) == 0) {
                int grow = row0 + wm * 64 + m * 16 + (lane >> 4) * 4 + r;
                ull pack = ((ull)fmap(bv) << 32) | (unsigned)bi;
                atomicMin(&packed[grow], pack);
            }
        }
    }
}

// ---------- fused merge + gather + loss partials ----------
__global__ __launch_bounds__(256) void gather_loss_k(const float* __restrict__ x,
    const float* __restrict__ cb, const ull* __restrict__ packed,
    const float* __restrict__ x2, float* __restrict__ outq,
    float* __restrict__ out_idx, float* __restrict__ out_mind,
    float* __restrict__ partials)
{
    __shared__ float ps[4];
    int gid  = blockIdx.x * blockDim.x + threadIdx.x;
    int row  = gid >> 6;
    int lane = threadIdx.x & 63;
    int w    = threadIdx.x >> 6;
    float s = 0.f;
    if (row < NROWS) {
        ull p = packed[row];                 // same-address within wave: broadcast
        int k = (int)(p & 0xffffffffull);
        if (lane == 0) {
            out_idx[row]  = (float)k;
            out_mind[row] = x2[row] + funmap((unsigned)(p >> 32));
        }
        const float4* q  = (const float4*)(cb + (size_t)k * DIM);
        const float4* xr = (const float4*)(x + (size_t)row * DIM);
        float4* o = (float4*)(outq + (size_t)row * DIM);
#pragma unroll
        for (int i = lane; i < DIM / 4; i += 64) {
            float4 qv = q[i], xv = xr[i];
            o[i] = qv;
            float dx = xv.x - qv.x, dy = xv.y - qv.y;
            float dz = xv.z - qv.z, dw = xv.w - qv.w;
            s += dx * dx + dy * dy + dz * dz + dw * dw;
        }
    }
#pragma unroll
    for (int off = 32; off > 0; off >>= 1) s += __shfl_down(s, off, 64);
    if (lane == 0) ps[w] = s;
    __syncthreads();
    if (threadIdx.x == 0) partials[blockIdx.x] = ps[0] + ps[1] + ps[2] + ps[3];
}

// ---------- final reduction of partials -> loss outputs ----------
__global__ __launch_bounds__(256) void finalize_k(const float* __restrict__ partials,
    float* __restrict__ out_loss, float* __restrict__ out_commit)
{
    __shared__ float ps[4];
    int t = threadIdx.x, lane = t & 63, w = t >> 6;
    float s = 0.f;
#pragma unroll
    for (int i = 0; i < NPART / 256; ++i) s += partials[t + 256 * i];
#pragma unroll
    for (int off = 32; off > 0; off >>= 1) s += __shfl_down(s, off, 64);
    if (lane == 0) ps[w] = s;
    __syncthreads();
    if (t == 0) {
        float tot = ps[0] + ps[1] + ps[2] + ps[3];
        *out_loss   = 0.25f * tot + tot;
        *out_commit = tot;
    }
}

// ================= fallback (fp32 path, small ws) =================
#define BM 64
#define BN 64
#define BK 32
#define KSPLIT 4
#define KPER (NUM_EMB / KSPLIT)
#define NCT (KPER / BN)

__global__ __launch_bounds__(256) void rowsumsq_k(const float* __restrict__ a,
                                                  float* __restrict__ out, int nrows)
{
    int gid  = blockIdx.x * blockDim.x + threadIdx.x;
    int row  = gid >> 6;
    int lane = threadIdx.x & 63;
    if (row >= nrows) return;
    const float4* r = (const float4*)(a + (size_t)row * DIM);
    float s = 0.f;
#pragma unroll
    for (int i = lane; i < DIM / 4; i += 64) {
        float4 v = r[i];
        s += v.x * v.x + v.y * v.y + v.z * v.z + v.w * v.w;
    }
#pragma unroll
    for (int off = 32; off > 0; off >>= 1) s += __shfl_down(s, off, 64);
    if (lane == 0) out[row] = s;
}

__global__ __launch_bounds__(256) void dist_argmin_old_k(const float* __restrict__ x,
    const float* __restrict__ cb, const float* __restrict__ e2,
    float* __restrict__ part_m, int* __restrict__ part_i)
{
    __shared__ __align__(16) float As[BK][BM + 4];
    __shared__ __align__(16) float Bs[BK][BN + 4];
    __shared__ float redv[BM][16];
    __shared__ int   redi[BM][16];

    const int row0 = blockIdx.x * BM;
    const int ks   = blockIdx.y;
    const int cbeg = ks * KPER;
    const int t    = threadIdx.x;
    const int tx   = t & 15;
    const int ty   = t >> 4;
    const int ld_d = t & 31;
    const int ld_r = t >> 5;

    float minm[4]; int mini[4];
#pragma unroll
    for (int i = 0; i < 4; ++i) { minm[i] = INFINITY; mini[i] = 0; }

    for (int ct = 0; ct < NCT; ++ct) {
        const int c0 = cbeg + ct * BN;
        float acc[4][4];
#pragma unroll
        for (int i = 0; i < 4; ++i)
#pragma unroll
            for (int j = 0; j < 4; ++j) acc[i][j] = 0.f;
        for (int dc = 0; dc < DIM; dc += BK) {
#pragma unroll
            for (int rr = 0; rr < BM; rr += 8)
                As[ld_d][ld_r + rr] = x[(size_t)(row0 + ld_r + rr) * DIM + dc + ld_d];
#pragma unroll
            for (int rr = 0; rr < BN; rr += 8)
                Bs[ld_d][ld_r + rr] = cb[(size_t)(c0 + ld_r + rr) * DIM + dc + ld_d];
            __syncthreads();
#pragma unroll
            for (int d = 0; d < BK; ++d) {
                float4 av = *(const float4*)&As[d][4 * ty];
                float4 bv = *(const float4*)&Bs[d][4 * tx];
                acc[0][0] += av.x * bv.x; acc[0][1] += av.x * bv.y;
                acc[0][2] += av.x * bv.z; acc[0][3] += av.x * bv.w;
                acc[1][0] += av.y * bv.x; acc[1][1] += av.y * bv.y;
                acc[1][2] += av.y * bv.z; acc[1][3] += av.y * bv.w;
                acc[2][0] += av.z * bv.x; acc[2][1] += av.z * bv.y;
                acc[2][2] += av.z * bv.z; acc[2][3] += av.z * bv.w;
                acc[3][0] += av.w * bv.x; acc[3][1] += av.w * bv.y;
                acc[3][2] += av.w * bv.z; acc[3][3] += av.w * bv.w;
            }
            __syncthreads();
        }
#pragma unroll
        for (int j = 0; j < 4; ++j) {
            const int c = c0 + 4 * tx + j;
            const float e = e2[c];
#pragma unroll
            for (int i = 0; i < 4; ++i) {
                float m = e - 2.f * acc[i][j];
                if (m < minm[i]) { minm[i] = m; mini[i] = c; }
            }
        }
    }
#pragma unroll
    for (int i = 0; i < 4; ++i) {
        redv[4 * ty + i][tx] = minm[i];
        redi[4 * ty + i][tx] = mini[i];
    }
    __syncthreads();
    if (t < BM) {
        float bm = INFINITY; int bi = 0;
#pragma unroll
        for (int c = 0; c < 16; ++c) {
            float v = redv[t][c];
            if (v < bm) { bm = v; bi = redi[t][c]; }
        }
        part_m[(size_t)(row0 + t) * KSPLIT + ks] = bm;
        part_i[(size_t)(row0 + t) * KSPLIT + ks] = bi;
    }
}

__global__ __launch_bounds__(256) void merge_pack_k(const float* __restrict__ part_m,
    const int* __restrict__ part_i, ull* __restrict__ packed)
{
    int row = blockIdx.x * blockDim.x + threadIdx.x;
    if (row >= NROWS) return;
    float bm = INFINITY; int bi = 0;
#pragma unroll
    for (int s = 0; s < KSPLIT; ++s) {
        float v = part_m[(size_t)row * KSPLIT + s];
        if (v < bm) { bm = v; bi = part_i[(size_t)row * KSPLIT + s]; }
    }
    packed[row] = ((ull)fmap(bm) << 32) | (unsigned)bi;
}

// ================= launch =================
extern "C" void kernel_launch(void* const* d_in, const int* in_sizes, int n_in,
                              void* d_out, int out_size, void* d_ws, size_t ws_size,
                              hipStream_t stream)
{
    const float* x  = (const float*)d_in[0];   // [16384, 512]
    const float* cb = (const float*)d_in[1];   // [8192, 512]
    float* out = (float*)d_out;

    float* outq       = out;
    float* out_loss   = out + 8388608;
    float* out_idx    = out + 8388609;
    float* out_mind   = out + 8388609 + 16384;
    float* out_commit = out + 8388609 + 2 * 16384;

    char* ws = (char*)d_ws;
    float* e2      = (float*)ws;   ws += NUM_EMB * 4;
    float* x2      = (float*)ws;   ws += NROWS * 4;
    ull*   packed  = (ull*)ws;     ws += NROWS * 8;
    float* partials= (float*)ws;   ws += NPART * 4;
    ushort* xh = (ushort*)ws;      ws += (size_t)NROWS * DIM * 2;
    ushort* xl = (ushort*)ws;      ws += (size_t)NROWS * DIM * 2;
    ushort* ch = (ushort*)ws;      ws += (size_t)NUM_EMB * DIM * 2;
    ushort* cl = (ushort*)ws;      ws += (size_t)NUM_EMB * DIM * 2;
    size_t need_fast = (size_t)(ws - (char*)d_ws);

    if (ws_size >= need_fast) {
        split_all_k<<<(NROWS + NUM_EMB) / 4, 256, 0, stream>>>(x, cb, xh, xl, ch, cl,
                                                               x2, e2, packed);
        dim3 grid(NROWS / 128, NUM_EMB / 128);
        dist_mfma_k<<<grid, 256, 0, stream>>>(xh, xl, ch, cl, e2, packed);
    } else {
        // fallback: fp32 path (small ws)
        rowsumsq_k<<<NUM_EMB / 4, 256, 0, stream>>>(cb, e2, NUM_EMB);
        rowsumsq_k<<<NROWS / 4, 256, 0, stream>>>(x, x2, NROWS);
        float* pm = (float*)((char*)d_ws + NUM_EMB * 4 + NROWS * 4 + NROWS * 8 + NPART * 4);
        int*   pi = (int*)(pm + (size_t)NROWS * KSPLIT);
        dim3 grid(NROWS / BM, KSPLIT);
        dist_argmin_old_k<<<grid, 256, 0, stream>>>(x, cb, e2, pm, pi);
        merge_pack_k<<<NROWS / 256, 256, 0, stream>>>(pm, pi, packed);
    }

    gather_loss_k<<<NROWS / 4, 256, 0, stream>>>(x, cb, packed, x2, outq,
                                                 out_idx, out_mind, partials);
    finalize_k<<<1, 256, 0, stream>>>(partials, out_loss, out_commit);
}

// Round 9
// 495.436 us; speedup vs baseline: 1.3523x; 1.3523x over previous
//
#include <hip/hip_runtime.h>
#include <hip/hip_bf16.h>
#include <math.h>

#define NUM_EMB 8192
#define DIM 512
#define NROWS 16384   // 32*512
#define NPART 4096    // gather_loss partial sums (one per block)

typedef unsigned short ushort;
typedef unsigned long long ull;
typedef __attribute__((ext_vector_type(8))) short short8;
typedef __attribute__((ext_vector_type(4))) float floatx4;

// ---------------- helpers ----------------
__device__ __forceinline__ ushort f2bf(float f) {
    unsigned u = __float_as_uint(f);
    unsigned r = (u + 0x7fffu + ((u >> 16) & 1u)) >> 16;   // RNE
    return (ushort)r;
}
__device__ __forceinline__ float bf2f(ushort h) {
    return __uint_as_float(((unsigned)h) << 16);
}
__device__ __forceinline__ unsigned fmap(float f) {       // monotone float->uint
    unsigned u = __float_as_uint(f);
    return (u & 0x80000000u) ? ~u : (u | 0x80000000u);
}
__device__ __forceinline__ float funmap(unsigned m) {
    return __uint_as_float((m & 0x80000000u) ? (m ^ 0x80000000u) : ~m);
}
__device__ __forceinline__ void gld16(const void* g, void* l) {
    __builtin_amdgcn_global_load_lds(
        (const __attribute__((address_space(1))) void*)g,
        (__attribute__((address_space(3))) void*)l, 16, 0, 0);
}

// Packed-A cell map (shared by split writer & dist reader):
//   P[elem] with elem = g*32768 + m*8192 + kk*512 + lane*8 + j
//   equals  x[(g*64 + m*16 + (lane&15))*512 + kk*32 + (lane>>4)*8 + j]
// (g = 64-row group, m = 16-row sub-tile, kk = K-tile of 32, lane = MFMA lane)

// ---------- fused split: x -> PACKED bf16 hi/lo, cb -> row-major hi/lo ----------
// + row sumsq + packed-argmin init. One wave per row.
__global__ __launch_bounds__(256) void split_all_k(const float* __restrict__ x,
    const float* __restrict__ cb,
    ushort* __restrict__ xhp, ushort* __restrict__ xlp,
    ushort* __restrict__ ch, ushort* __restrict__ cl,
    float* __restrict__ x2, float* __restrict__ e2, ull* __restrict__ packed)
{
    int gid  = blockIdx.x * blockDim.x + threadIdx.x;
    int row  = gid >> 6;
    int lane = threadIdx.x & 63;
    if (row >= NROWS + NUM_EMB) return;
    float s = 0.f;
    if (row < NROWS) {
        // x path: whole row in one pass; lane covers elems lane*8..+8
        const int r  = row;
        const int g  = r >> 6, m = (r >> 4) & 3, lr = r & 15;
        const int kk = lane >> 2, seg = lane & 3;
        const float4* rp = (const float4*)(x + (size_t)r * DIM);
        float4 va = rp[2 * lane], vb = rp[2 * lane + 1];
        float v[8] = {va.x, va.y, va.z, va.w, vb.x, vb.y, vb.z, vb.w};
        short8 hv, lv;
#pragma unroll
        for (int j = 0; j < 8; ++j) {
            s += v[j] * v[j];
            ushort h = f2bf(v[j]);
            hv[j] = (short)h;
            lv[j] = (short)f2bf(v[j] - bf2f(h));
        }
        const size_t dest = (size_t)g * 32768 + m * 8192 + kk * 512 + (seg * 16 + lr) * 8;
        *(short8*)(xhp + dest) = hv;
        *(short8*)(xlp + dest) = lv;
#pragma unroll
        for (int off = 32; off > 0; off >>= 1) s += __shfl_down(s, off, 64);
        if (lane == 0) { x2[r] = s; packed[r] = ~0ull; }
    } else {
        // cb path: row-major hi/lo (B is LDS-staged in dist)
        const int r = row - NROWS;
        const float4* rp = (const float4*)(cb + (size_t)r * DIM);
        ushort4* h4 = (ushort4*)(ch + (size_t)r * DIM);
        ushort4* l4 = (ushort4*)(cl + (size_t)r * DIM);
#pragma unroll
        for (int i = lane; i < DIM / 4; i += 64) {
            float4 v = rp[i];
            s += v.x * v.x + v.y * v.y + v.z * v.z + v.w * v.w;
            ushort4 h, l;
            h.x = f2bf(v.x); l.x = f2bf(v.x - bf2f(h.x));
            h.y = f2bf(v.y); l.y = f2bf(v.y - bf2f(h.y));
            h.z = f2bf(v.z); l.z = f2bf(v.z - bf2f(h.z));
            h.w = f2bf(v.w); l.w = f2bf(v.w - bf2f(h.w));
            h4[i] = h; l4[i] = l;
        }
#pragma unroll
        for (int off = 32; off > 0; off >>= 1) s += __shfl_down(s, off, 64);
        if (lane == 0) e2[r] = s;
    }
}

// ---------- MFMA distance + argmin (16x16x32 bf16, 3-pass hi/lo split) ----------
// grid (64, 128): x = code tile, y = row tile (consecutive blocks share A tile).
// B staged via LDS with R4's 0-conflict XOR swizzle; A read DIRECT from the
// packed layout: one contiguous 1KB global_load_dwordx4 per fragment, double-
// buffered one full kk-tile ahead (fixes R8's 58-cyc prefetch distance).
__global__ __launch_bounds__(256, 3) void dist_mfma_k(
    const ushort* __restrict__ xhp, const ushort* __restrict__ xlp,
    const ushort* __restrict__ ch, const ushort* __restrict__ cl,
    const float* __restrict__ e2, ull* __restrict__ packed)
{
    __shared__ ushort Bh[128 * 32];   // 8 KB
    __shared__ ushort Bl[128 * 32];   // 8 KB

    const int tid  = threadIdx.x;
    const int lane = tid & 63;
    const int w    = tid >> 6;
    const int wm   = w >> 1, wn = w & 1;
    const int col0 = blockIdx.x * 128;
    const int row0 = blockIdx.y * 128;
    const int g    = blockIdx.y * 2 + wm;   // 64-row group of this wave's A

    floatx4 acc[4][4];
#pragma unroll
    for (int m = 0; m < 4; ++m)
#pragma unroll
        for (int n = 0; n < 4; ++n) acc[m][n] = (floatx4){0.f, 0.f, 0.f, 0.f};

    // B staging chunk map (R4): chunk c -> row c>>2, LDS cell c&3 at elem-off c*8;
    // global segment fetched = (c&3) ^ ((c>>3)&3)
    const int c0 = tid, c1 = tid + 256;
    const int gb0 = (col0 + (c0 >> 2)) * DIM + (((c0 & 3) ^ ((c0 >> 3) & 3)) * 8);
    const int gb1 = (col0 + (c1 >> 2)) * DIM + (((c1 & 3) ^ ((c1 >> 3) & 3)) * 8);
    const int l0 = c0 * 8, l1 = c1 * 8;

    // B fragment base: row (lane&15), cell (lane>>4) ^ ((lane>>1)&3)
    const int fr = (lane & 15) * 32 + (((lane >> 4) ^ ((lane >> 1) & 3)) * 8);

    // A packed bases: elem = g*32768 + m*8192 + kk*512 + lane*8
    const ushort* Abh = xhp + (size_t)g * 32768 + lane * 8;
    const ushort* Abl = xlp + (size_t)g * 32768 + lane * 8;

    // prologue: A tile kk=0
    short8 Ahc[4], Alc[4];
#pragma unroll
    for (int m = 0; m < 4; ++m) {
        Ahc[m] = *(const short8*)(Abh + m * 8192);
        Alc[m] = *(const short8*)(Abl + m * 8192);
    }

    for (int kk = 0; kk < 16; ++kk) {
        const int dk = kk * 32;
        __syncthreads();   // prev LDS reads done (also drains our A prefetch)
        gld16(&ch[gb0 + dk], &Bh[l0]);  gld16(&ch[gb1 + dk], &Bh[l1]);
        gld16(&cl[gb0 + dk], &Bl[l0]);  gld16(&cl[gb1 + dk], &Bl[l1]);
        __syncthreads();   // B staged

        // prefetch next A tile (full kk ahead: ~300+ wave-cycles of cover)
        const int kn = (kk < 15) ? (kk + 1) : 15;
        short8 Ahn[4], Aln[4];
#pragma unroll
        for (int m = 0; m < 4; ++m) {
            Ahn[m] = *(const short8*)(Abh + m * 8192 + kn * 512);
            Aln[m] = *(const short8*)(Abl + m * 8192 + kn * 512);
        }

        short8 bh[4], bl[4];
#pragma unroll
        for (int n = 0; n < 4; ++n) {
            const int o = (wn * 64 + n * 16) * 32 + fr;
            bh[n] = *(const short8*)&Bh[o];
            bl[n] = *(const short8*)&Bl[o];
        }

#pragma unroll
        for (int m = 0; m < 4; ++m)
#pragma unroll
            for (int n = 0; n < 4; ++n) {
                acc[m][n] = __builtin_amdgcn_mfma_f32_16x16x32_bf16(Ahc[m], bh[n], acc[m][n], 0, 0, 0);
                acc[m][n] = __builtin_amdgcn_mfma_f32_16x16x32_bf16(Ahc[m], bl[n], acc[m][n], 0, 0, 0);
                acc[m][n] = __builtin_amdgcn_mfma_f32_16x16x32_bf16(Alc[m], bh[n], acc[m][n], 0, 0, 0);
            }
#pragma unroll
        for (int m = 0; m < 4; ++m) { Ahc[m] = Ahn[m]; Alc[m] = Aln[m]; }
    }

    // epilogue: v = e2[c] - 2*dot ; argmin with first-occurrence tie-break
    float e2v[4];
    int   cidx[4];
#pragma unroll
    for (int n = 0; n < 4; ++n) {
        cidx[n] = col0 + wn * 64 + n * 16 + (lane & 15);
        e2v[n]  = e2[cidx[n]];
    }
#pragma unroll
    for (int m = 0; m < 4; ++m) {
#pragma unroll
        for (int r = 0; r < 4; ++r) {
            float bv = INFINITY; int bi = 0x7fffffff;
#pragma unroll
            for (int n = 0; n < 4; ++n) {        // ascending code order
                float v = e2v[n] - 2.f * acc[m][n][r];
                if (v < bv) { bv = v; bi = cidx[n]; }
            }
#pragma unroll
            for (int mk = 1; mk < 16; mk <<= 1) {  // 16-lane butterfly (same quad group)
                float ov = __shfl_xor(bv, mk, 64);
                int   oi = __shfl_xor(bi, mk, 64);
                if (ov < bv || (ov == bv && oi < bi)) { bv = ov; bi = oi; }
            }
            if ((lane & 15) == 0) {
                int grow = row0 + wm * 64 + m * 16 + (lane >> 4) * 4 + r;
                ull pack = ((ull)fmap(bv) << 32) | (unsigned)bi;
                atomicMin(&packed[grow], pack);
            }
        }
    }
}

// ---------- fused merge + gather + loss partials ----------
__global__ __launch_bounds__(256) void gather_loss_k(const float* __restrict__ x,
    const float* __restrict__ cb, const ull* __restrict__ packed,
    const float* __restrict__ x2, float* __restrict__ outq,
    float* __restrict__ out_idx, float* __restrict__ out_mind,
    float* __restrict__ partials)
{
    __shared__ float ps[4];
    int gid  = blockIdx.x * blockDim.x + threadIdx.x;
    int row  = gid >> 6;
    int lane = threadIdx.x & 63;
    int w    = threadIdx.x >> 6;
    float s = 0.f;
    if (row < NROWS) {
        ull p = packed[row];                 // same-address within wave: broadcast
        int k = (int)(p & 0xffffffffull);
        if (lane == 0) {
            out_idx[row]  = (float)k;
            out_mind[row] = x2[row] + funmap((unsigned)(p >> 32));
        }
        const float4* q  = (const float4*)(cb + (size_t)k * DIM);
        const float4* xr = (const float4*)(x + (size_t)row * DIM);
        float4* o = (float4*)(outq + (size_t)row * DIM);
#pragma unroll
        for (int i = lane; i < DIM / 4; i += 64) {
            float4 qv = q[i], xv = xr[i];
            o[i] = qv;
            float dx = xv.x - qv.x, dy = xv.y - qv.y;
            float dz = xv.z - qv.z, dw = xv.w - qv.w;
            s += dx * dx + dy * dy + dz * dz + dw * dw;
        }
    }
#pragma unroll
    for (int off = 32; off > 0; off >>= 1) s += __shfl_down(s, off, 64);
    if (lane == 0) ps[w] = s;
    __syncthreads();
    if (threadIdx.x == 0) partials[blockIdx.x] = ps[0] + ps[1] + ps[2] + ps[3];
}

// ---------- final reduction of partials -> loss outputs ----------
__global__ __launch_bounds__(256) void finalize_k(const float* __restrict__ partials,
    float* __restrict__ out_loss, float* __restrict__ out_commit)
{
    __shared__ float ps[4];
    int t = threadIdx.x, lane = t & 63, w = t >> 6;
    float s = 0.f;
#pragma unroll
    for (int i = 0; i < NPART / 256; ++i) s += partials[t + 256 * i];
#pragma unroll
    for (int off = 32; off > 0; off >>= 1) s += __shfl_down(s, off, 64);
    if (lane == 0) ps[w] = s;
    __syncthreads();
    if (t == 0) {
        float tot = ps[0] + ps[1] + ps[2] + ps[3];
        *out_loss   = 0.25f * tot + tot;
        *out_commit = tot;
    }
}

// ================= fallback (fp32 path, small ws) =================
#define BM 64
#define BN 64
#define BK 32
#define KSPLIT 4
#define KPER (NUM_EMB / KSPLIT)
#define NCT (KPER / BN)

__global__ __launch_bounds__(256) void rowsumsq_k(const float* __restrict__ a,
                                                  float* __restrict__ out, int nrows)
{
    int gid  = blockIdx.x * blockDim.x + threadIdx.x;
    int row  = gid >> 6;
    int lane = threadIdx.x & 63;
    if (row >= nrows) return;
    const float4* r = (const float4*)(a + (size_t)row * DIM);
    float s = 0.f;
#pragma unroll
    for (int i = lane; i < DIM / 4; i += 64) {
        float4 v = r[i];
        s += v.x * v.x + v.y * v.y + v.z * v.z + v.w * v.w;
    }
#pragma unroll
    for (int off = 32; off > 0; off >>= 1) s += __shfl_down(s, off, 64);
    if (lane == 0) out[row] = s;
}

__global__ __launch_bounds__(256) void dist_argmin_old_k(const float* __restrict__ x,
    const float* __restrict__ cb, const float* __restrict__ e2,
    float* __restrict__ part_m, int* __restrict__ part_i)
{
    __shared__ __align__(16) float As[BK][BM + 4];
    __shared__ __align__(16) float Bs[BK][BN + 4];
    __shared__ float redv[BM][16];
    __shared__ int   redi[BM][16];

    const int row0 = blockIdx.x * BM;
    const int ks   = blockIdx.y;
    const int cbeg = ks * KPER;
    const int t    = threadIdx.x;
    const int tx   = t & 15;
    const int ty   = t >> 4;
    const int ld_d = t & 31;
    const int ld_r = t >> 5;

    float minm[4]; int mini[4];
#pragma unroll
    for (int i = 0; i < 4; ++i) { minm[i] = INFINITY; mini[i] = 0; }

    for (int ct = 0; ct < NCT; ++ct) {
        const int c0 = cbeg + ct * BN;
        float acc[4][4];
#pragma unroll
        for (int i = 0; i < 4; ++i)
#pragma unroll
            for (int j = 0; j < 4; ++j) acc[i][j] = 0.f;
        for (int dc = 0; dc < DIM; dc += BK) {
#pragma unroll
            for (int rr = 0; rr < BM; rr += 8)
                As[ld_d][ld_r + rr] = x[(size_t)(row0 + ld_r + rr) * DIM + dc + ld_d];
#pragma unroll
            for (int rr = 0; rr < BN; rr += 8)
                Bs[ld_d][ld_r + rr] = cb[(size_t)(c0 + ld_r + rr) * DIM + dc + ld_d];
            __syncthreads();
#pragma unroll
            for (int d = 0; d < BK; ++d) {
                float4 av = *(const float4*)&As[d][4 * ty];
                float4 bv = *(const float4*)&Bs[d][4 * tx];
                acc[0][0] += av.x * bv.x; acc[0][1] += av.x * bv.y;
                acc[0][2] += av.x * bv.z; acc[0][3] += av.x * bv.w;
                acc[1][0] += av.y * bv.x; acc[1][1] += av.y * bv.y;
                acc[1][2] += av.y * bv.z; acc[1][3] += av.y * bv.w;
                acc[2][0] += av.z * bv.x; acc[2][1] += av.z * bv.y;
                acc[2][2] += av.z * bv.z; acc[2][3] += av.z * bv.w;
                acc[3][0] += av.w * bv.x; acc[3][1] += av.w * bv.y;
                acc[3][2] += av.w * bv.z; acc[3][3] += av.w * bv.w;
            }
            __syncthreads();
        }
#pragma unroll
        for (int j = 0; j < 4; ++j) {
            const int c = c0 + 4 * tx + j;
            const float e = e2[c];
#pragma unroll
            for (int i = 0; i < 4; ++i) {
                float m = e - 2.f * acc[i][j];
                if (m < minm[i]) { minm[i] = m; mini[i] = c; }
            }
        }
    }
#pragma unroll
    for (int i = 0; i < 4; ++i) {
        redv[4 * ty + i][tx] = minm[i];
        redi[4 * ty + i][tx] = mini[i];
    }
    __syncthreads();
    if (t < BM) {
        float bm = INFINITY; int bi = 0;
#pragma unroll
        for (int c = 0; c < 16; ++c) {
            float v = redv[t][c];
            if (v < bm) { bm = v; bi = redi[t][c]; }
        }
        part_m[(size_t)(row0 + t) * KSPLIT + ks] = bm;
        part_i[(size_t)(row0 + t) * KSPLIT + ks] = bi;
    }
}

__global__ __launch_bounds__(256) void merge_pack_k(const float* __restrict__ part_m,
    const int* __restrict__ part_i, ull* __restrict__ packed)
{
    int row = blockIdx.x * blockDim.x + threadIdx.x;
    if (row >= NROWS) return;
    float bm = INFINITY; int bi = 0;
#pragma unroll
    for (int s = 0; s < KSPLIT; ++s) {
        float v = part_m[(size_t)row * KSPLIT + s];
        if (v < bm) { bm = v; bi = part_i[(size_t)row * KSPLIT + s]; }
    }
    packed[row] = ((ull)fmap(bm) << 32) | (unsigned)bi;
}

// ================= launch =================
extern "C" void kernel_launch(void* const* d_in, const int* in_sizes, int n_in,
                              void* d_out, int out_size, void* d_ws, size_t ws_size,
                              hipStream_t stream)
{
    const float* x  = (const float*)d_in[0];   // [16384, 512]
    const float* cb = (const float*)d_in[1];   // [8192, 512]
    float* out = (float*)d_out;

    float* outq       = out;
    float* out_loss   = out + 8388608;
    float* out_idx    = out + 8388609;
    float* out_mind   = out + 8388609 + 16384;
    float* out_commit = out + 8388609 + 2 * 16384;

    char* ws = (char*)d_ws;
    float* e2      = (float*)ws;   ws += NUM_EMB * 4;
    float* x2      = (float*)ws;   ws += NROWS * 4;
    ull*   packed  = (ull*)ws;     ws += NROWS * 8;
    float* partials= (float*)ws;   ws += NPART * 4;
    ushort* xhp = (ushort*)ws;     ws += (size_t)NROWS * DIM * 2;
    ushort* xlp = (ushort*)ws;     ws += (size_t)NROWS * DIM * 2;
    ushort* ch  = (ushort*)ws;     ws += (size_t)NUM_EMB * DIM * 2;
    ushort* cl  = (ushort*)ws;     ws += (size_t)NUM_EMB * DIM * 2;
    size_t need_fast = (size_t)(ws - (char*)d_ws);

    if (ws_size >= need_fast) {
        split_all_k<<<(NROWS + NUM_EMB) / 4, 256, 0, stream>>>(x, cb, xhp, xlp, ch, cl,
                                                               x2, e2, packed);
        dim3 grid(NUM_EMB / 128, NROWS / 128);   // x = code tile, y = row tile
        dist_mfma_k<<<grid, 256, 0, stream>>>(xhp, xlp, ch, cl, e2, packed);
    } else {
        // fallback: fp32 path (small ws)
        rowsumsq_k<<<NUM_EMB / 4, 256, 0, stream>>>(cb, e2, NUM_EMB);
        rowsumsq_k<<<NROWS / 4, 256, 0, stream>>>(x, x2, NROWS);
        float* pm = (float*)((char*)d_ws + NUM_EMB * 4 + NROWS * 4 + NROWS * 8 + NPART * 4);
        int*   pi = (int*)(pm + (size_t)NROWS * KSPLIT);
        dim3 grid(NROWS / BM, KSPLIT);
        dist_argmin_old_k<<<grid, 256, 0, stream>>>(x, cb, e2, pm, pi);
        merge_pack_k<<<NROWS / 256, 256, 0, stream>>>(pm, pi, packed);
    }

    gather_loss_k<<<NROWS / 4, 256, 0, stream>>>(x, cb, packed, x2, outq,
                                                 out_idx, out_mind, partials);
    finalize_k<<<1, 256, 0, stream>>>(partials, out_loss, out_commit);
}